// Round 12
// baseline (335.841 us; speedup 1.0000x reference)
//
#include <hip/hip_runtime.h>
#include <hip/hip_bf16.h>

#define SEQ   28
#define BATCH 8192
#define NIN   28
#define HID   128
#define NOUT  10

// gate pre-scales folded into weights/bias at pack time:
// i,f,o rows scaled by -log2(e)  -> exp2(z) = e^{-x}  (sigmoid denom)
// g rows scaled by +2*log2(e)    -> exp2(z) = e^{2x}  (tanh)
#define SCL_SIG  (-1.4426950408889634f)
#define SCL_TANH (2.8853900817779268f)

typedef __bf16 bf16_t;
typedef __bf16 bf16x8 __attribute__((ext_vector_type(8)));
typedef float  f32x4  __attribute__((ext_vector_type(4)));

// XOR-swizzle for row-major [rows][128] bf16 tiles (256B rows).
__device__ __forceinline__ unsigned swz(unsigned row, unsigned byte_in_row) {
    return row * 256u + (byte_in_row ^ ((row & 7u) << 4));
}

// LDS-only barrier (all per-step cross-wave traffic is LDS; never drain vmcnt).
__device__ __forceinline__ void barrier_lds() {
    asm volatile("s_waitcnt lgkmcnt(0)\n\ts_barrier" ::: "memory");
}

// Pack {Whh0, Whh1, Wih1} [512][128] fp32 -> frag-linear bf16 with per-gate
// scaling. frag index (ks*32+nt)*64+lane, elem j: gate = nt*16+(lane&15),
// k = ks*32+(lane>>4)*8+j.
__global__ void pack_w_kernel(const float* __restrict__ Whh0, bf16_t* __restrict__ o0,
                              const float* __restrict__ Whh1, bf16_t* __restrict__ o1,
                              const float* __restrict__ Wih1, bf16_t* __restrict__ o2) {
    int idx = blockIdx.x * 256 + threadIdx.x;      // 0 .. 3*65536-1
    int mi = idx >> 16;
    int e  = idx & 65535;
    const float* W = (mi == 0) ? Whh0 : (mi == 1) ? Whh1 : Wih1;
    bf16_t*      o = (mi == 0) ? o0   : (mi == 1) ? o1   : o2;
    int j    = e & 7;
    int frag = e >> 3;
    int lane = frag & 63;
    int ksnt = frag >> 6;
    int nt = ksnt & 31, ks = ksnt >> 5;
    int gate = nt * 16 + (lane & 15);
    int k    = ks * 32 + ((lane >> 4) << 3) + j;
    float s  = ((gate >> 7) == 2) ? SCL_TANH : SCL_SIG;
    o[e] = (bf16_t)(W[gate * 128 + k] * s);
}

// Load one L0 x A-frag (fp32 X row, K padded 28->32) into bf16x8.
__device__ __forceinline__ bf16x8 load_x0(const float* __restrict__ X,
                                          int t, int rb, int m, int l15, int l4) {
    const float* base = X + ((size_t)(t * BATCH + rb + 16 * m + l15)) * NIN + l4 * 8;
    f32x4 lo = *(const f32x4*)base;
    f32x4 hi = {0.f, 0.f, 0.f, 0.f};
    if (l4 < 3) hi = *(const f32x4*)(base + 4);
    bf16x8 v;
    #pragma unroll
    for (int j = 0; j < 4; ++j) { v[j] = (bf16_t)lo[j]; v[4 + j] = (bf16_t)hi[j]; }
    return v;
}

// Vectorized LSTM activation for one m-slice: z[0..3] = pre-scaled gate
// preacts (i,f,g,o), c updated in place, h (bf16) written to buf rows
// [rowbase, rowbase+4) col byte colb. 5 exp2 + 2 rcp per element; all
// non-trans arithmetic f32x4 (v_pk ops).
__device__ __forceinline__ void act_store(f32x4 (&z)[4], f32x4& c,
                                          unsigned char* buf, int rowbase, int colb)
{
    f32x4 Ei, Ef, Eg, Eo;
    #pragma unroll
    for (int r = 0; r < 4; ++r) {
        Ei[r] = __builtin_amdgcn_exp2f(z[0][r]);   // e^{-zi}
        Ef[r] = __builtin_amdgcn_exp2f(z[1][r]);   // e^{-zf}
        Eg[r] = __builtin_amdgcn_exp2f(z[2][r]);   // e^{2zg}
        Eo[r] = __builtin_amdgcn_exp2f(z[3][r]);   // e^{-zo}
    }
    f32x4 ti = Ei + 1.0f, tf = Ef + 1.0f;
    f32x4 tg = Eg + 1.0f, to = Eo + 1.0f;
    f32x4 titg = ti * tg;
    f32x4 num  = c * titg + tf * (tg - 2.0f);
    f32x4 den  = tf * titg;
    f32x4 rif;
    #pragma unroll
    for (int r = 0; r < 4; ++r) rif[r] = __builtin_amdgcn_rcpf(den[r]);
    f32x4 cn = num * rif;
    c = cn;
    f32x4 e2 = cn * SCL_TANH;
    f32x4 Ec;
    #pragma unroll
    for (int r = 0; r < 4; ++r) Ec[r] = __builtin_amdgcn_exp2f(e2[r]);
    f32x4 dh = to * (Ec + 1.0f);
    f32x4 rh;
    #pragma unroll
    for (int r = 0; r < 4; ++r) rh[r] = __builtin_amdgcn_rcpf(dh[r]);
    f32x4 hvf = (Ec - 1.0f) * rh;
    #pragma unroll
    for (int r = 0; r < 4; ++r)
        *(bf16_t*)(buf + swz(rowbase + r, colb)) = (bf16_t)hvf[r];
}

// LDS map (155648 B total):
//   [0, 131072)        whh0 B-frags, frag-linear (ds_read_b128 streamed)
//   [131072, 147456)   h0 double buffer (2 x [32][128] bf16, swizzled)
//   [147456, 155648)   h2 single buffer ([32][128] bf16, swizzled)
#define OFF_H0 131072
#define OFF_H2 147456

// One pipelined step s: L1 computes its timestep t1 = s-1 (x-input = h0(s-1),
// which is ALSO L0's recurrent input — same LDS buffer, same frag reads);
// L0 computes timestep t0 = s. Barrier #1 (top) publishes h0(s-1) and
// h2(s-2); barrier #2 separates block-wide h2 reads from h2 writes (h2 is
// single-buffered). Wave w owns gate tiles {w, w+8, w+16, w+24} (i,f,g,o of
// h-cols [16w,16w+16)) for both layers.
template <int PAR, bool DO_L0, bool DO_L1>
__device__ __forceinline__ void step_pipe(
    int s, int rb, int tid, int w, int l15, int l4,
    unsigned char* smem,
    const float* __restrict__ X,
    bf16x8 (&wih0)[4],                    // L0 x-weights (KS=1), regs
    bf16x8 (&whh1)[4][4], bf16x8 (&wih1)[4][4],   // L1 weights, regs
    float (&bias0)[4], float (&bias1)[4],
    f32x4 (&c0)[2], f32x4 (&c1)[2],
    bf16x8 (&x0)[2])
{
    unsigned char* h0r = smem + OFF_H0 + ((PAR ^ 1) << 13);  // h0(s-1)
    unsigned char* h0w = smem + OFF_H0 + (PAR << 13);        // receives h0(s)
    unsigned char* h2b = smem + OFF_H2;                      // h2 (single)
    const int colb = (16 * w + l15) * 2;

    barrier_lds();   // #1: h0(s-1) and h2(s-2) writes visible block-wide

    // ================= L1: timestep s-1 =================
    if constexpr (DO_L1) {
        f32x4 acc1[2][4];
        #pragma unroll
        for (int m = 0; m < 2; ++m)
            #pragma unroll
            for (int q = 0; q < 4; ++q) {
                f32x4 b = {bias1[q], bias1[q], bias1[q], bias1[q]};
                acc1[m][q] = b;
            }
        // acc1 += Wih1·h1(s-1) + Whh1·h2(s-2); h1(s-1) == h0(s-1) frags
        #pragma unroll
        for (int ks = 0; ks < 4; ++ks) {
            bf16x8 hA[2], h2A[2];
            #pragma unroll
            for (int m = 0; m < 2; ++m) {
                hA[m]  = *(const bf16x8*)(h0r + swz(16 * m + l15, (ks * 32 + l4 * 8) * 2));
                h2A[m] = *(const bf16x8*)(h2b + swz(16 * m + l15, (ks * 32 + l4 * 8) * 2));
            }
            #pragma unroll
            for (int m = 0; m < 2; ++m)
                #pragma unroll
                for (int q = 0; q < 4; ++q) {
                    acc1[m][q] = __builtin_amdgcn_mfma_f32_16x16x32_bf16(
                        hA[m], wih1[q][ks], acc1[m][q], 0, 0, 0);
                    acc1[m][q] = __builtin_amdgcn_mfma_f32_16x16x32_bf16(
                        h2A[m], whh1[q][ks], acc1[m][q], 0, 0, 0);
                }
        }
        barrier_lds();   // #2: all waves' h2 reads complete before h2 writes
        #pragma unroll
        for (int m = 0; m < 2; ++m)
            act_store(acc1[m], c1[m], h2b, 16 * m + l4 * 4, colb);
    }

    // ================= L0: timestep s =================
    if constexpr (DO_L0) {
        f32x4 acc0[2][4];
        #pragma unroll
        for (int m = 0; m < 2; ++m)
            #pragma unroll
            for (int q = 0; q < 4; ++q) {
                f32x4 b = {bias0[q], bias0[q], bias0[q], bias0[q]};
                acc0[m][q] = __builtin_amdgcn_mfma_f32_16x16x32_bf16(
                    x0[m], wih0[q], b, 0, 0, 0);
            }
        // acc0 += Whh0·h0(s-1); whh0 B-frags streamed from LDS per ks
        #pragma unroll
        for (int ks = 0; ks < 4; ++ks) {
            bf16x8 hA[2];
            #pragma unroll
            for (int m = 0; m < 2; ++m)
                hA[m] = *(const bf16x8*)(h0r + swz(16 * m + l15, (ks * 32 + l4 * 8) * 2));
            bf16x8 wB[4];
            #pragma unroll
            for (int q = 0; q < 4; ++q)
                wB[q] = *(const bf16x8*)(smem + ((unsigned)((ks * 32 + (w + 8 * q)) * 64 + (tid & 63))) * 16u);
            #pragma unroll
            for (int m = 0; m < 2; ++m)
                #pragma unroll
                for (int q = 0; q < 4; ++q)
                    acc0[m][q] = __builtin_amdgcn_mfma_f32_16x16x32_bf16(
                        hA[m], wB[q], acc0[m][q], 0, 0, 0);
        }
        #pragma unroll
        for (int m = 0; m < 2; ++m)
            act_store(acc0[m], c0[m], h0w, 16 * m + l4 * 4, colb);

        // prefetch x(s+1) into the just-freed x regs
        if (s + 1 < SEQ) {
            #pragma unroll
            for (int m = 0; m < 2; ++m)
                x0[m] = load_x0(X, s + 1, rb, m, l15, l4);
        }
    }
}

// Fused layer-pipelined 2-layer LSTM: one block = 32 batch rows, 8 waves,
// 1 block/CU. L0 and L1 run concurrently with a 1-step lag: 29 barrier
// phases instead of 56, h1 never touches HBM (it IS the h0 LDS buffer).
// whh0 in LDS (128 KB); wih0/whh1/wih1 register-resident.
__global__ __launch_bounds__(512, 2)
void lstm_pipe_kernel(const float* __restrict__ Wih0,
                      const float* __restrict__ bih0, const float* __restrict__ bhh0,
                      const float* __restrict__ bih1, const float* __restrict__ bhh1,
                      const float* __restrict__ X,
                      const bf16_t* __restrict__ whhp0,
                      const bf16_t* __restrict__ whhp1,
                      const bf16_t* __restrict__ wihp1,
                      const float* __restrict__ Wlin, const float* __restrict__ blin,
                      float* __restrict__ out)
{
    __shared__ unsigned char smem[155648] __attribute__((aligned(16)));

    const int tid  = threadIdx.x;
    const int lane = tid & 63;
    const int w    = tid >> 6;
    const int l15  = lane & 15;
    const int l4   = lane >> 4;
    const int rb   = blockIdx.x * 32;

    bf16x8 wih0[4], whh1[4][4], wih1[4][4];
    float  bias0[4], bias1[4];
    f32x4  c0[2], c1[2];
    bf16x8 x0[2];

    // ---- whh0 -> LDS (packed frag-linear, raw 16B copies) ----
    for (int i = tid * 16; i < 131072; i += 512 * 16)
        *(f32x4*)(smem + i) = *(const f32x4*)((const unsigned char*)whhp0 + i);
    // ---- zero h0 double buffer + h2 buffer (24 KB) ----
    for (int i = tid * 16; i < 24576; i += 512 * 16) {
        f32x4 z = {0.f, 0.f, 0.f, 0.f};
        *(f32x4*)(smem + OFF_H0 + i) = z;
    }
    // ---- register weights ----
    #pragma unroll
    for (int q = 0; q < 4; ++q)
        #pragma unroll
        for (int ks = 0; ks < 4; ++ks) {
            whh1[q][ks] = *(const bf16x8*)(whhp1 + ((size_t)((ks * 32 + (w + 8 * q)) * 64 + lane)) * 8);
            wih1[q][ks] = *(const bf16x8*)(wihp1 + ((size_t)((ks * 32 + (w + 8 * q)) * 64 + lane)) * 8);
        }
    #pragma unroll
    for (int q = 0; q < 4; ++q) {
        int gate = 16 * w + 128 * q + l15;
        float s = (q == 2) ? SCL_TANH : SCL_SIG;
        #pragma unroll
        for (int j = 0; j < 8; ++j) {
            int k = l4 * 8 + j;
            wih0[q][j] = (k < NIN) ? (bf16_t)(Wih0[gate * NIN + k] * s) : (bf16_t)0.0f;
        }
        bias0[q] = (bih0[gate] + bhh0[gate]) * s;
        bias1[q] = (bih1[gate] + bhh1[gate]) * s;
    }
    {
        f32x4 z = {0.f, 0.f, 0.f, 0.f};
        c0[0] = z; c0[1] = z; c1[0] = z; c1[1] = z;
    }
    // ---- x(0) ----
    #pragma unroll
    for (int m = 0; m < 2; ++m)
        x0[m] = load_x0(X, 0, rb, m, l15, l4);
    __syncthreads();   // LDS init visible

    // ---- pipelined steps: s=0 L0-only; s=1..27 both; s=28 L1-only ----
    step_pipe<0, true, false>(0, rb, tid, w, l15, l4, smem, X,
                              wih0, whh1, wih1, bias0, bias1, c0, c1, x0);
    for (int s = 1; s <= 25; s += 2) {
        step_pipe<1, true, true>(s,     rb, tid, w, l15, l4, smem, X,
                                 wih0, whh1, wih1, bias0, bias1, c0, c1, x0);
        step_pipe<0, true, true>(s + 1, rb, tid, w, l15, l4, smem, X,
                                 wih0, whh1, wih1, bias0, bias1, c0, c1, x0);
    }
    step_pipe<1, true,  true>(27, rb, tid, w, l15, l4, smem, X,
                              wih0, whh1, wih1, bias0, bias1, c0, c1, x0);
    step_pipe<0, false, true>(28, rb, tid, w, l15, l4, smem, X,
                              wih0, whh1, wih1, bias0, bias1, c0, c1, x0);

    barrier_lds();   // h2(27) writes visible

    // ---- head: pred = h2(27) @ W_lin^T + b_lin ----
    if (tid < 32 * NOUT) {
        int row = tid / NOUT, oc = tid % NOUT;
        const unsigned char* hf = smem + OFF_H2;
        float s = blin[oc];
        #pragma unroll 8
        for (int k = 0; k < HID; ++k) {
            float h = (float)*(const bf16_t*)(hf + swz(row, k * 2));
            s += h * Wlin[oc * HID + k];
        }
        out[(size_t)(rb + row) * NOUT + oc] = s;
    }
}

extern "C" void kernel_launch(void* const* d_in, const int* in_sizes, int n_in,
                              void* d_out, int out_size, void* d_ws, size_t ws_size,
                              hipStream_t stream) {
    const float* X    = (const float*)d_in[0];
    const float* Wih0 = (const float*)d_in[1];
    const float* Whh0 = (const float*)d_in[2];
    const float* bih0 = (const float*)d_in[3];
    const float* bhh0 = (const float*)d_in[4];
    const float* Wih1 = (const float*)d_in[5];
    const float* Whh1 = (const float*)d_in[6];
    const float* bih1 = (const float*)d_in[7];
    const float* bhh1 = (const float*)d_in[8];
    const float* Wlin = (const float*)d_in[9];
    const float* blin = (const float*)d_in[10];
    float* out = (float*)d_out;

    unsigned char* ws = (unsigned char*)d_ws;
    bf16_t* whhp0 = (bf16_t*)(ws);            // 131,072 B
    bf16_t* whhp1 = (bf16_t*)(ws + 131072);   // 131,072 B
    bf16_t* wihp1 = (bf16_t*)(ws + 262144);   // 131,072 B

    pack_w_kernel<<<dim3(768), dim3(256), 0, stream>>>(Whh0, whhp0, Whh1, whhp1, Wih1, wihp1);

    lstm_pipe_kernel<<<dim3(256), dim3(512), 0, stream>>>(
        Wih0, bih0, bhh0, bih1, bhh1, X, whhp0, whhp1, wihp1,
        Wlin, blin, out);
}

// Round 13
// 119.068 us; speedup vs baseline: 2.8206x; 2.8206x over previous
//
#include <hip/hip_runtime.h>
#include <hip/hip_bf16.h>

#define SEQ   28
#define BATCH 8192
#define NIN   28
#define HID   128
#define NOUT  10

// gate pre-scales folded into weights/bias at pack time:
// i,f,o rows scaled by -log2(e)  -> exp2(z) = e^{-x}  (sigmoid denom)
// g rows scaled by +2*log2(e)    -> exp2(z) = e^{2x}  (tanh)
#define SCL_SIG  (-1.4426950408889634f)
#define SCL_TANH (2.8853900817779268f)

typedef __bf16 bf16_t;
typedef __bf16 bf16x8 __attribute__((ext_vector_type(8)));
typedef float  f32x4  __attribute__((ext_vector_type(4)));

// XOR-swizzle for row-major [rows][128] bf16 tiles (256B rows).
__device__ __forceinline__ unsigned swz(unsigned row, unsigned byte_in_row) {
    return row * 256u + (byte_in_row ^ ((row & 7u) << 4));
}

// Per-step barrier: LDS-only drain (cross-wave traffic inside a step is LDS).
__device__ __forceinline__ void barrier_lds() {
    asm volatile("s_waitcnt lgkmcnt(0)\n\ts_barrier" ::: "memory");
}

// Pack {Whh0, Whh1, Wih1} [512][128] fp32 -> frag-linear bf16 with per-gate
// scaling. frag index (ks*32+nt)*64+lane, elem j: gate = nt*16+(lane&15),
// k = ks*32+(lane>>4)*8+j.
__global__ void pack_w_kernel(const float* __restrict__ Whh0, bf16_t* __restrict__ o0,
                              const float* __restrict__ Whh1, bf16_t* __restrict__ o1,
                              const float* __restrict__ Wih1, bf16_t* __restrict__ o2) {
    int idx = blockIdx.x * 256 + threadIdx.x;      // 0 .. 3*65536-1
    int mi = idx >> 16;
    int e  = idx & 65535;
    const float* W = (mi == 0) ? Whh0 : (mi == 1) ? Whh1 : Wih1;
    bf16_t*      o = (mi == 0) ? o0   : (mi == 1) ? o1   : o2;
    int j    = e & 7;
    int frag = e >> 3;
    int lane = frag & 63;
    int ksnt = frag >> 6;
    int nt = ksnt & 31, ks = ksnt >> 5;
    int gate = nt * 16 + (lane & 15);
    int k    = ks * 32 + ((lane >> 4) << 3) + j;
    float s  = ((gate >> 7) == 2) ? SCL_TANH : SCL_SIG;
    o[e] = (bf16_t)(W[gate * 128 + k] * s);
}

// Load one L0 x A-frag (fp32 X row, K padded 28->32) into bf16x8.
__device__ __forceinline__ bf16x8 load_x0(const float* __restrict__ X,
                                          int t, int rb, int m, int l15, int l4) {
    const float* base = X + ((size_t)(t * BATCH + rb + 16 * m + l15)) * NIN + l4 * 8;
    f32x4 lo = *(const f32x4*)base;
    f32x4 hi = {0.f, 0.f, 0.f, 0.f};
    if (l4 < 3) hi = *(const f32x4*)(base + 4);
    bf16x8 v;
    #pragma unroll
    for (int j = 0; j < 4; ++j) { v[j] = (bf16_t)lo[j]; v[4 + j] = (bf16_t)hi[j]; }
    return v;
}

// One LSTM step, overlap-structured (round-6 validated schedule):
//   barrier; [L0: stream h(t-1)->h1]; ds_read h(t-1); h-MFMA into accIn;
//   per m-slice: {vectorized trans(t) from accIn[m]  ||  x-MFMA(t+1) into
//   accOut[m]}; issue x(t+2) loads.
// Activation arithmetic is written as f32x4 ext-vector ops so hipcc emits
// v_pk_{add,mul,fma}_f32 (2 f32/lane/instr) for every non-trans op; exp2/rcp
// remain scalar per component (no packed transcendentals on CDNA4).
template <int LAYER>
__device__ __forceinline__ void step_v2(
    int t, int rb, int tid, int w, int l15, int l4,
    unsigned char* smem,
    const float* __restrict__ X, const bf16_t* __restrict__ h1r,
    bf16_t* __restrict__ h1w,
    bf16x8 (&whh)[4][4], bf16x8 (&wih)[4][4],
    f32x4 (&biasv)[4], f32x4 (&c)[2],
    bf16x8 (&x)[4][2],
    f32x4 (&accIn)[2][4], f32x4 (&accOut)[2][4])
{
    constexpr int KS = (LAYER == 0) ? 1 : 4;
    unsigned char* hb = smem + ((~t & 1) << 13);   // holds h(t-1)
    unsigned char* hn = smem + ((t & 1) << 13);    // receives h(t)

    barrier_lds();   // all waves' h(t-1) LDS writes complete & visible

    // ---- L0: stream h(t-1) to global h1 (reads hb, now consistent) ----
    if constexpr (LAYER == 0) {
        if (t >= 1) {
            int row = tid >> 4, sc = tid & 15;
            f32x4 v = *(const f32x4*)(hb + swz(row, sc * 16));
            *(f32x4*)((unsigned char*)h1w + ((size_t)((t - 1) * BATCH + rb + row)) * 256 + sc * 16) = v;
        }
    }

    // ---- h-part MFMAs (ks-chunked: 4 a-frags live at a time) ----
    #pragma unroll
    for (int kc = 0; kc < 2; ++kc) {
        bf16x8 a0[2], a1[2];
        #pragma unroll
        for (int m = 0; m < 2; ++m) {
            a0[m] = *(const bf16x8*)(hb + swz(16 * m + l15, ((2 * kc) * 32 + l4 * 8) * 2));
            a1[m] = *(const bf16x8*)(hb + swz(16 * m + l15, ((2 * kc + 1) * 32 + l4 * 8) * 2));
        }
        #pragma unroll
        for (int m = 0; m < 2; ++m)
            #pragma unroll
            for (int q = 0; q < 4; ++q) {
                accIn[m][q] = __builtin_amdgcn_mfma_f32_16x16x32_bf16(
                    a0[m], whh[q][2 * kc], accIn[m][q], 0, 0, 0);
                accIn[m][q] = __builtin_amdgcn_mfma_f32_16x16x32_bf16(
                    a1[m], whh[q][2 * kc + 1], accIn[m][q], 0, 0, 0);
            }
    }

    // ---- per m-slice: vectorized activations(t) || x-part MFMAs for t+1 ----
    #pragma unroll
    for (int m = 0; m < 2; ++m) {
        // activations: 5 exp2 + 2 rcp per element; all non-trans ops f32x4
        f32x4 Ei, Ef, Eg, Eo;
        #pragma unroll
        for (int r = 0; r < 4; ++r) {
            Ei[r] = __builtin_amdgcn_exp2f(accIn[m][0][r]);   // e^{-zi}
            Ef[r] = __builtin_amdgcn_exp2f(accIn[m][1][r]);   // e^{-zf}
            Eg[r] = __builtin_amdgcn_exp2f(accIn[m][2][r]);   // e^{2zg}
            Eo[r] = __builtin_amdgcn_exp2f(accIn[m][3][r]);   // e^{-zo}
        }
        f32x4 ti = Ei + 1.0f, tf = Ef + 1.0f;
        f32x4 tg = Eg + 1.0f, to = Eo + 1.0f;
        f32x4 titg = ti * tg;
        f32x4 num  = c[m] * titg + tf * (tg - 2.0f);
        f32x4 den  = tf * titg;
        f32x4 rif;
        #pragma unroll
        for (int r = 0; r < 4; ++r) rif[r] = __builtin_amdgcn_rcpf(den[r]);
        f32x4 cn = num * rif;
        c[m] = cn;
        f32x4 e2 = cn * SCL_TANH;
        f32x4 Ec;
        #pragma unroll
        for (int r = 0; r < 4; ++r) Ec[r] = __builtin_amdgcn_exp2f(e2[r]);
        f32x4 dh = to * (Ec + 1.0f);
        f32x4 rh;
        #pragma unroll
        for (int r = 0; r < 4; ++r) rh[r] = __builtin_amdgcn_rcpf(dh[r]);
        f32x4 hvf = (Ec - 1.0f) * rh;
        #pragma unroll
        for (int r = 0; r < 4; ++r)
            *(bf16_t*)(hn + swz(16 * m + l4 * 4 + r, (16 * w + l15) * 2)) = (bf16_t)hvf[r];

        // x-part MFMAs for t+1 (independent of h(t); consumes x(t+1) regs)
        #pragma unroll
        for (int q = 0; q < 4; ++q) {
            accOut[m][q] = biasv[q];
            #pragma unroll
            for (int ks = 0; ks < KS; ++ks)
                accOut[m][q] = __builtin_amdgcn_mfma_f32_16x16x32_bf16(
                    x[ks][m], wih[q][ks], accOut[m][q], 0, 0, 0);
        }
    }

    // ---- issue x(t+2) loads into the just-freed x regs ----
    if (t + 2 < SEQ) {
        if constexpr (LAYER == 0) {
            #pragma unroll
            for (int m = 0; m < 2; ++m)
                x[0][m] = load_x0(X, t + 2, rb, m, l15, l4);
        } else {
            #pragma unroll
            for (int ks = 0; ks < 4; ++ks)
                #pragma unroll
                for (int m = 0; m < 2; ++m)
                    x[ks][m] = *(const bf16x8*)(h1r + ((size_t)((t + 2) * BATCH + rb + 16 * m + l15)) * HID + ks * 32 + l4 * 8);
        }
    }
}

// Fused 2-layer LSTM: one block = 32 batch rows through BOTH layers.
// 8 waves, 1 block/CU. Weights register-resident (frag-linear preload).
__global__ __launch_bounds__(512, 2)
void lstm_fused_kernel(const float* __restrict__ Wih0,
                       const float* __restrict__ bih0, const float* __restrict__ bhh0,
                       const float* __restrict__ bih1, const float* __restrict__ bhh1,
                       const float* __restrict__ X,
                       const bf16_t* __restrict__ whhp0,
                       const bf16_t* __restrict__ whhp1,
                       const bf16_t* __restrict__ wihp1,
                       bf16_t* __restrict__ h1,
                       const float* __restrict__ Wlin, const float* __restrict__ blin,
                       float* __restrict__ out)
{
    __shared__ unsigned char smem[16384] __attribute__((aligned(16)));

    const int tid  = threadIdx.x;
    const int lane = tid & 63;
    const int w    = tid >> 6;
    const int l15  = lane & 15;
    const int l4   = lane >> 4;
    const int rb   = blockIdx.x * 32;

    bf16x8 whh[4][4], wih[4][4];
    f32x4  biasv[4];
    f32x4  c[2];
    bf16x8 x[4][2];
    f32x4  accA[2][4], accB[2][4];

    // ================= phase 0: layer 0 =================
    #pragma unroll
    for (int q = 0; q < 4; ++q)
        #pragma unroll
        for (int ks = 0; ks < 4; ++ks)
            whh[q][ks] = *(const bf16x8*)(whhp0 + ((size_t)((ks * 32 + (w + 8 * q)) * 64 + lane)) * 8);
    #pragma unroll
    for (int q = 0; q < 4; ++q) {
        int gate = 16 * w + 128 * q + l15;
        float s = (q == 2) ? SCL_TANH : SCL_SIG;
        #pragma unroll
        for (int j = 0; j < 8; ++j) {
            int k = l4 * 8 + j;
            wih[q][0][j] = (k < NIN) ? (bf16_t)(Wih0[gate * NIN + k] * s) : (bf16_t)0.0f;
        }
        float b = (bih0[gate] + bhh0[gate]) * s;
        f32x4 bv = {b, b, b, b};
        biasv[q] = bv;
    }
    {
        f32x4 z = {0.f, 0.f, 0.f, 0.f};
        c[0] = z; c[1] = z;
    }
    // zero both h buffers
    for (int i = tid * 16; i < 16384; i += 512 * 16) {
        f32x4 z = {0.f, 0.f, 0.f, 0.f};
        *(f32x4*)(smem + i) = z;
    }
    // accA = bias + x(0)-part; then prefetch x(1)
    #pragma unroll
    for (int m = 0; m < 2; ++m)
        x[0][m] = load_x0(X, 0, rb, m, l15, l4);
    #pragma unroll
    for (int m = 0; m < 2; ++m)
        #pragma unroll
        for (int q = 0; q < 4; ++q)
            accA[m][q] = __builtin_amdgcn_mfma_f32_16x16x32_bf16(
                x[0][m], wih[q][0], biasv[q], 0, 0, 0);
    #pragma unroll
    for (int m = 0; m < 2; ++m)
        x[0][m] = load_x0(X, 1, rb, m, l15, l4);
    // body(0)'s top barrier makes the zero-init visible

    for (int t = 0; t < SEQ; t += 2) {
        step_v2<0>(t,     rb, tid, w, l15, l4, smem, X, nullptr, h1,
                   whh, wih, biasv, c, x, accA, accB);
        step_v2<0>(t + 1, rb, tid, w, l15, l4, smem, X, nullptr, h1,
                   whh, wih, biasv, c, x, accB, accA);
    }

    // final h(27) -> h1, then full drain before phase 1
    barrier_lds();
    {
        int row = tid >> 4, sc = tid & 15;
        f32x4 v = *(const f32x4*)(smem + 8192 + swz(row, sc * 16));  // buf1 = h(27)
        *(f32x4*)((unsigned char*)h1 + ((size_t)(27 * BATCH + rb + row)) * 256 + sc * 16) = v;
    }
    __syncthreads();   // h1 global stores drained (vmcnt) before L1 reads

    // ================= phase 1: layer 1 =================
    #pragma unroll
    for (int q = 0; q < 4; ++q) {
        #pragma unroll
        for (int ks = 0; ks < 4; ++ks) {
            whh[q][ks] = *(const bf16x8*)(whhp1 + ((size_t)((ks * 32 + (w + 8 * q)) * 64 + lane)) * 8);
            wih[q][ks] = *(const bf16x8*)(wihp1 + ((size_t)((ks * 32 + (w + 8 * q)) * 64 + lane)) * 8);
        }
        int gate = 16 * w + 128 * q + l15;
        float s = (q == 2) ? SCL_TANH : SCL_SIG;
        float b = (bih1[gate] + bhh1[gate]) * s;
        f32x4 bv = {b, b, b, b};
        biasv[q] = bv;
    }
    {
        f32x4 z = {0.f, 0.f, 0.f, 0.f};
        c[0] = z; c[1] = z;
    }
    // re-zero both h buffers (L0 left h-state in them)
    for (int i = tid * 16; i < 16384; i += 512 * 16) {
        f32x4 z = {0.f, 0.f, 0.f, 0.f};
        *(f32x4*)(smem + i) = z;
    }
    // accA = bias + x(0)-part from h1; then prefetch x(1)
    #pragma unroll
    for (int ks = 0; ks < 4; ++ks)
        #pragma unroll
        for (int m = 0; m < 2; ++m)
            x[ks][m] = *(const bf16x8*)(h1 + ((size_t)(rb + 16 * m + l15)) * HID + ks * 32 + l4 * 8);
    #pragma unroll
    for (int m = 0; m < 2; ++m)
        #pragma unroll
        for (int q = 0; q < 4; ++q) {
            accA[m][q] = biasv[q];
            #pragma unroll
            for (int ks = 0; ks < 4; ++ks)
                accA[m][q] = __builtin_amdgcn_mfma_f32_16x16x32_bf16(
                    x[ks][m], wih[q][ks], accA[m][q], 0, 0, 0);
        }
    #pragma unroll
    for (int ks = 0; ks < 4; ++ks)
        #pragma unroll
        for (int m = 0; m < 2; ++m)
            x[ks][m] = *(const bf16x8*)(h1 + ((size_t)(BATCH + rb + 16 * m + l15)) * HID + ks * 32 + l4 * 8);
    // body(0)'s top barrier makes the re-zero visible

    for (int t = 0; t < SEQ; t += 2) {
        step_v2<1>(t,     rb, tid, w, l15, l4, smem, nullptr, h1, nullptr,
                   whh, wih, biasv, c, x, accA, accB);
        step_v2<1>(t + 1, rb, tid, w, l15, l4, smem, nullptr, h1, nullptr,
                   whh, wih, biasv, c, x, accB, accA);
    }
    barrier_lds();   // h2(27) in buf1 consistent

    // ---- epilogue: pred = h2[27] @ W_lin^T + b_lin ----
    if (tid < 32 * NOUT) {
        int row = tid / NOUT, oc = tid % NOUT;
        const unsigned char* hf = smem + 8192;   // buf1 = h2(27)
        float s = blin[oc];
        #pragma unroll 8
        for (int k = 0; k < HID; ++k) {
            float h = (float)*(const bf16_t*)(hf + swz(row, k * 2));
            s += h * Wlin[oc * HID + k];
        }
        out[(size_t)(rb + row) * NOUT + oc] = s;
    }
}

extern "C" void kernel_launch(void* const* d_in, const int* in_sizes, int n_in,
                              void* d_out, int out_size, void* d_ws, size_t ws_size,
                              hipStream_t stream) {
    const float* X    = (const float*)d_in[0];
    const float* Wih0 = (const float*)d_in[1];
    const float* Whh0 = (const float*)d_in[2];
    const float* bih0 = (const float*)d_in[3];
    const float* bhh0 = (const float*)d_in[4];
    const float* Wih1 = (const float*)d_in[5];
    const float* Whh1 = (const float*)d_in[6];
    const float* bih1 = (const float*)d_in[7];
    const float* bhh1 = (const float*)d_in[8];
    const float* Wlin = (const float*)d_in[9];
    const float* blin = (const float*)d_in[10];
    float* out = (float*)d_out;

    unsigned char* ws = (unsigned char*)d_ws;
    bf16_t* h1    = (bf16_t*)(ws);                       // 58,720,256 B
    bf16_t* whhp0 = (bf16_t*)(ws + 58720256);            //    131,072 B
    bf16_t* whhp1 = (bf16_t*)(ws + 58851328);            //    131,072 B
    bf16_t* wihp1 = (bf16_t*)(ws + 58982400);            //    131,072 B

    pack_w_kernel<<<dim3(768), dim3(256), 0, stream>>>(Whh0, whhp0, Whh1, whhp1, Wih1, wihp1);

    lstm_fused_kernel<<<dim3(256), dim3(512), 0, stream>>>(
        Wih0, bih0, bhh0, bih1, bhh1, X, whhp0, whhp1, wihp1, h1,
        Wlin, blin, out);
}